// Round 6
// baseline (359.449 us; speedup 1.0000x reference)
//
#include <hip/hip_runtime.h>

// Problem constants (fixed by setup_inputs)
constexpr int B = 4, Q = 100, C = 40, Cp1 = 41, HW = 65536;

// R4: single-WAVE blocks. 2048 blocks = 4 b x 512 segments of 128 px; 64 thr.
// No __syncthreads in the hot loop (single wave -> LDS RAW ordered by
// compiler lgkmcnt), no barrier ever drains the prefetch vmcnt queue.
// 8 independent waves/CU stream concurrently (R1-R3 were grid-starved at
// 2 blocks/CU with 14 barriers/block -> convoy stalls).
constexpr int FBLKS = 2048;

// Workspace layout (4-byte words):
//  [0, 16000)        counts    u32 [B][Q][C]
//  [16000, 16160)    tsum      u32 [B][C]
//  [16160]           ce_sum    f32
//  [16161]           n_valid   u32
//  [16162, 32562)    inter_ext f32 [B*Q][41]   (col 40 = ignored-pixel sig sum)
constexpr int WS_WORDS = 32562;

typedef __attribute__((ext_vector_type(8))) short short8;   // 8 bf16
typedef __attribute__((ext_vector_type(4))) float f32x4;

__device__ __forceinline__ short f2bf(float f) {            // RNE f32->bf16
    unsigned u = __float_as_uint(f);
    u += 0x7FFF + ((u >> 16) & 1);
    return (short)(u >> 16);
}

__global__ void kZ(unsigned* __restrict__ ws, int n) {
    int i = blockIdx.x * blockDim.x + threadIdx.x;
    for (; i < n; i += gridDim.x * blockDim.x) ws[i] = 0u;
}

__global__ __launch_bounds__(64, 2) void kF(const float* __restrict__ masks,
                                            const int* __restrict__ targets,
                                            unsigned* __restrict__ counts,
                                            unsigned* __restrict__ tsum,
                                            float* __restrict__ ce_sum,
                                            unsigned* __restrict__ n_valid,
                                            float* __restrict__ inter_ext) {
    // tile row = q (16 rows x 256B); swizzle byte-in-row ^= ((row&7)<<4):
    //  write: 64 lanes x 4B cover the row -> 2-way banks (free)
    //  read (A-frag ds_read_b128): 8 distinct 16B slots per 8 rows -> 2-way
    __shared__ __align__(16) short tileS[16 * 128];          // 4 KiB
    __shared__ __align__(8) unsigned char tgt8[128];
    __shared__ unsigned ts_local[C];

    const int l = threadIdx.x;              // 0..63 (single wave)
    const int m = l & 15, quad = l >> 4;

    const int blk = blockIdx.x;
    const int b = blk >> 9;                 // 0..3
    const int seg = blk & 511;              // 0..511
    const int pxb = 2 * l;                  // px within block [0,128)
    const int p0 = seg * 128 + pxb;         // px within image

    // ---- prologue: targets -> LDS bytes; ts_local zero ----
    const int2 tg = *(const int2*)(targets + (size_t)b * HW + p0);
    const int tg0 = tg.x, tg1 = tg.y;
    *(unsigned short*)&tgt8[pxb] =
        (unsigned short)((tg0 & 255) | ((tg1 & 255) << 8));
    if (l < C) ts_local[l] = 0u;
    __syncthreads();                        // once; prefetch not yet issued

    const float* mp = masks + (size_t)b * Q * HW + p0;

    // ---- issue tile-0 prefetch (16 float2 in flight) ----
    float2 vvA[16], vvB[16];
    #pragma unroll
    for (int u = 0; u < 16; ++u)
        vvA[u] = *(const float2*)(mp + (size_t)u * HW);

    // ---- prebuild one-hot B frags in REGISTERS (48 VGPR, 12 short8) ----
    // bv[ct][kc][j] = (target[kc*32+quad*8+j] == ct*16+m) ? 1.0bf : 0
    // ct=2: m==8 -> 255 (ignored col 40); m>8 -> cv 41..47 never matches.
    short8 bv[3][4];
    #pragma unroll
    for (int ct = 0; ct < 3; ++ct) {
        const int cv = (ct == 2 && m == 8) ? 255 : (ct * 16 + m);
        #pragma unroll
        for (int kc = 0; kc < 4; ++kc) {
            const unsigned long long tw =
                *(const unsigned long long*)&tgt8[kc * 32 + quad * 8];
            short8 v;
            #pragma unroll
            for (int j = 0; j < 8; ++j)
                v[j] = ((int)((tw >> (8 * j)) & 255) == cv) ? (short)0x3F80
                                                            : (short)0;
            bv[ct][kc] = v;
        }
    }

    // per-pixel softmax state (2 px/thread) — formulas/order == verified A-part
    float m20 = -INFINITY, m21 = -INFINITY;
    float s0 = 0.f, s1 = 0.f, xt0 = 0.f, xt1 = 0.f;
    int am0 = 0, am1 = 0;

    char* tb = (char*)tileS;
    const int wrbase = 4 * l;               // my px-pair byte offset within row

    #pragma unroll
    for (int qt = 0; qt < 7; ++qt) {
        const int nu = (qt == 6) ? 4 : 16;

        // ---- issue NEXT tile's loads (no barrier ever drains them) ----
        if (qt < 6) {
            const int nn = (qt == 5) ? 4 : 16;
            const float* mq = mp + (size_t)((qt + 1) * 16) * HW;
            #pragma unroll
            for (int u = 0; u < 16; ++u)
                if (u < nn) vvB[u] = *(const float2*)(mq + (size_t)u * HW);
        }

        // ---- process current tile: softmax state + sigmoid->bf16 tile ----
        #pragma unroll
        for (int u = 0; u < 16; ++u)
            if (u < nu) {
                const int q = qt * 16 + u;
                const float v0 = vvA[u].x, v1 = vvA[u].y;
                s0 += __expf(v0);
                s1 += __expf(v1);
                am0 = (v0 > m20) ? q : am0;  m20 = fmaxf(m20, v0);
                am1 = (v1 > m21) ? q : am1;  m21 = fmaxf(m21, v1);
                xt0 = (q == tg0) ? v0 : xt0;
                xt1 = (q == tg1) ? v1 : xt1;
                const float g0 = __builtin_amdgcn_rcpf(1.f + __expf(-v0));
                const float g1 = __builtin_amdgcn_rcpf(1.f + __expf(-v1));
                const unsigned pk = (unsigned)(unsigned short)f2bf(g0) |
                                    ((unsigned)(unsigned short)f2bf(g1) << 16);
                *(unsigned*)(tb + ((u * 256 + wrbase) ^ ((u & 7) << 4))) = pk;
            }
        // single wave: compiler inserts lgkmcnt before dependent ds_reads.

        // ---- MFMA phase: A from tile, B from register one-hot ----
        #pragma unroll
        for (int ct = 0; ct < 3; ++ct) {
            f32x4 acc = {0.f, 0.f, 0.f, 0.f};
            #pragma unroll
            for (int kc = 0; kc < 4; ++kc) {
                const short8 av = *(const short8*)(tb +
                    ((m * 256 + kc * 64 + quad * 16) ^ ((m & 7) << 4)));
                acc = __builtin_amdgcn_mfma_f32_16x16x32_bf16(av, bv[ct][kc],
                                                              acc, 0, 0, 0);
            }
            // epilogue: D row = quad*4+reg (q), col = m (+16*ct)
            if (!(ct == 2 && m > 8)) {
                #pragma unroll
                for (int reg = 0; reg < 4; ++reg) {
                    const int q = qt * 16 + quad * 4 + reg;
                    if (q < 100)
                        atomicAdd(&inter_ext[(size_t)(b * Q + q) * Cp1 +
                                             ct * 16 + m], acc[reg]);
                }
            }
        }

        // rotate double-buffer (renamed away by full unroll)
        #pragma unroll
        for (int u = 0; u < 16; ++u) vvA[u] = vvB[u];
    }

    // ---- softmax epilogue (identical math to verified A-part) ----
    float ce = 0.f;
    unsigned nv = 0u;
    if (tg0 != 255) {
        ce += __logf(s0) - xt0; nv++;
        atomicAdd(&counts[((size_t)b * Q + am0) * C + tg0], 1u);
        atomicAdd(&ts_local[tg0], 1u);
    }
    if (tg1 != 255) {
        ce += __logf(s1) - xt1; nv++;
        atomicAdd(&counts[((size_t)b * Q + am1) * C + tg1], 1u);
        atomicAdd(&ts_local[tg1], 1u);
    }
    for (int off = 32; off; off >>= 1) {
        ce += __shfl_xor(ce, off);
        nv += __shfl_xor(nv, off);
    }
    if (l == 0) {
        atomicAdd(ce_sum, ce);
        atomicAdd(n_valid, nv);
    }
    __syncthreads();                        // ts_local atomics -> reads
    if (l < C) {
        unsigned t = ts_local[l];
        if (t) atomicAdd(&tsum[b * C + l], t);
    }
}

// Kernel C: finalize. src_sum derived from inter_ext's 41 columns. (Verified R11.)
__global__ __launch_bounds__(512) void kC(const float* __restrict__ logits,
                                          const unsigned* __restrict__ counts,
                                          const unsigned* __restrict__ tsum,
                                          const float* __restrict__ inter_ext,
                                          const float* __restrict__ ce_sum,
                                          const unsigned* __restrict__ n_valid,
                                          float* __restrict__ out) {
    int tid = threadIdx.x;
    __shared__ float dice_sum[C];
    __shared__ float ssum[B * Q];
    __shared__ float wred[8];
    __shared__ float s_lce;
    if (tid < C) dice_sum[tid] = 0.f;
    if (tid < B * Q) {                     // src_sum[bq] = sum of all 41 cols
        const float* r = inter_ext + (size_t)tid * Cp1;
        float t = 0.f;
        #pragma unroll
        for (int c = 0; c < Cp1; ++c) t += r[c];
        ssum[tid] = t;
    }

    float ce_acc = 0.f;
    for (int i = tid; i < B * Q; i += 512) {
        const unsigned* cnt = counts + (size_t)i * C;
        unsigned best = 0;
        int tc = C;
        #pragma unroll
        for (int c = 0; c < C; ++c) {
            unsigned v = cnt[c];
            if (v > best) { best = v; tc = c; }
        }
        if (tc != C) {
            const float* lg = logits + (size_t)i * Cp1;
            float mm = -INFINITY, xt = 0.f;
            #pragma unroll
            for (int c = 0; c < Cp1; ++c) {
                float v = lg[c];
                mm = fmaxf(mm, v);
                if (c == tc) xt = v;
            }
            float ss = 0.f;
            #pragma unroll
            for (int c = 0; c < Cp1; ++c) ss += __expf(lg[c] - mm);
            float nll = mm + __logf(ss) - xt;
            float p = __expf(-nll);
            float om = 1.f - p;
            ce_acc += om * om * nll;
        }
    }
    for (int off = 32; off; off >>= 1) ce_acc += __shfl_xor(ce_acc, off);
    if ((tid & 63) == 0) wred[tid >> 6] = ce_acc;
    __syncthreads();                        // also publishes ssum + dice_sum init
    if (tid == 0) {
        float t = 0.f;
        for (int w = 0; w < 8; ++w) t += wred[w];
        s_lce = t;
    }

    for (int i = tid; i < B * Q * C; i += 512) {
        int bq = i / C, c = i - bq * C;
        float denom = ssum[bq] + (float)tsum[(bq / Q) * C + c] + 1e-8f;
        atomicAdd(&dice_sum[c], 2.f * inter_ext[(size_t)bq * Cp1 + c] / denom);
    }
    __syncthreads();

    if (tid == 0) {
        float dl = 0.f;
        for (int c = 0; c < C; ++c) {
            unsigned ts = tsum[c] + tsum[C + c] + tsum[2 * C + c] + tsum[3 * C + c];
            if (ts > 0) dl += 1.f - dice_sum[c] * (1.f / (B * Q));
        }
        dl *= (1.f / C);
        float ce_mask = ce_sum[0] / fmaxf((float)n_valid[0], 1.f);
        float lce = s_lce * (1.f / (B * Q));
        out[0] = 2.f * lce + 5.f * ce_mask + 5.f * dl;
    }
}

extern "C" void kernel_launch(void* const* d_in, const int* in_sizes, int n_in,
                              void* d_out, int out_size, void* d_ws, size_t ws_size,
                              hipStream_t stream) {
    const float* logits  = (const float*)d_in[0];   // [B,Q,41] f32
    const float* masks   = (const float*)d_in[1];   // [B,Q,H,W] f32
    const int*   targets = (const int*)d_in[2];     // [B,H,W] int32
    float* out = (float*)d_out;                     // f32 scalar

    unsigned* ws        = (unsigned*)d_ws;
    unsigned* counts    = ws;                       // 16000 u32
    unsigned* tsum      = ws + 16000;               // 160 u32
    float*    ce_sum    = (float*)(ws + 16160);     // 1 f32
    unsigned* n_valid   = ws + 16161;               // 1 u32
    float*    inter_ext = (float*)(ws + 16162);     // 16400 f32

    kZ<<<64, 256, 0, stream>>>(ws, WS_WORDS);
    kF<<<FBLKS, 64, 0, stream>>>(masks, targets, counts, tsum, ce_sum, n_valid,
                                 inter_ext);
    kC<<<1, 512, 0, stream>>>(logits, counts, tsum, inter_ext, ce_sum, n_valid, out);
}

// Round 7
// 212.851 us; speedup vs baseline: 1.6887x; 1.6887x over previous
//
#include <hip/hip_runtime.h>

// Problem constants (fixed by setup_inputs)
constexpr int B = 4, Q = 100, C = 40, Cp1 = 41, HW = 65536;

// R5: 8-wave blocks, 1 px/thread. 512 blocks = 4 b x 128 segments of 512 px.
// vs verified R2 (77us): occupancy 8 -> 16 waves/CU, barriers 14 -> 8 (double-
// buffered tile), JIT loads kept (R2's proven non-spilling codegen; R3/R4's
// register double-buffers spilled to scratch: WRITE_SIZE 50/93 MB). All MFMA
// inputs, atomic counts, and softmax formulas bit-identical to R2.
constexpr int FBLKS = 512;

// Workspace layout (4-byte words):
//  [0, 16000)        counts    u32 [B][Q][C]
//  [16000, 16160)    tsum      u32 [B][C]
//  [16160]           ce_sum    f32
//  [16161]           n_valid   u32
//  [16162, 32562)    inter_ext f32 [B*Q][41]   (col 40 = ignored-pixel sig sum)
constexpr int WS_WORDS = 32562;

typedef __attribute__((ext_vector_type(8))) short short8;   // 8 bf16
typedef __attribute__((ext_vector_type(4))) float f32x4;

__device__ __forceinline__ short f2bf(float f) {            // RNE f32->bf16
    unsigned u = __float_as_uint(f);
    u += 0x7FFF + ((u >> 16) & 1);
    return (short)(u >> 16);
}

__global__ void kZ(unsigned* __restrict__ ws, int n) {
    int i = blockIdx.x * blockDim.x + threadIdx.x;
    for (; i < n; i += gridDim.x * blockDim.x) ws[i] = 0u;
}

__global__ __launch_bounds__(512) void kF(const float* __restrict__ masks,
                                          const int* __restrict__ targets,
                                          unsigned* __restrict__ counts,
                                          unsigned* __restrict__ tsum,
                                          float* __restrict__ ce_sum,
                                          unsigned* __restrict__ n_valid,
                                          float* __restrict__ inter_ext) {
    // tile row = q (16 rows x 1024 B); swizzle byte-in-row ^= ((row&7)<<4)
    // (verified R2 formula) so A-frag ds_read_b128 is conflict-light.
    __shared__ __align__(16) short tileS[2][16 * 512];       // 2 x 16 KiB
    __shared__ __align__(8) unsigned char tgt8[512];
    __shared__ unsigned ts_local[C];
    __shared__ float cred[8];
    __shared__ unsigned vred[8];

    const int tid = threadIdx.x;            // 0..511
    const int l = tid & 63, w = tid >> 6;   // wave 0..7
    const int m = l & 15, quad = l >> 4;

    const int blk = blockIdx.x;
    const int b = blk >> 7;                 // 0..3
    const int seg = blk & 127;              // 0..127
    const int p0 = seg * 512 + tid;         // px within image

    // ---- prologue: targets -> LDS bytes; ts_local zero ----
    // (tgt8/ts_local first consumed after the qt=0 __syncthreads)
    const int tgv = targets[(size_t)b * HW + p0];
    tgt8[tid] = (unsigned char)(tgv & 255);
    if (tid < C) ts_local[tid] = 0u;

    const float* mp = masks + (size_t)b * Q * HW + p0;

    // per-pixel softmax state (1 px/thread) — formulas/order == verified R2
    float m2 = -INFINITY, s = 0.f, xt = 0.f;
    int am = 0;

    // wave MFMA role: w0 cols 0-15, w1 16-31, w2 32-40 (m>8 dead), w3-7 none
    const int cv = (w == 2 && m == 8) ? 255 : (w * 16 + m);

    for (int qt = 0; qt < 7; ++qt) {
        char* tbq = (char*)(&tileS[qt & 1][0]);
        const int nu = (qt == 6) ? 4 : 16;

        // ---- JIT loads, 16 in flight (16 VGPR batch; R2-proven shape) ----
        float vv[16];
        #pragma unroll
        for (int u = 0; u < 16; ++u)
            if (u < nu) vv[u] = mp[(size_t)(qt * 16 + u) * HW];

        // ---- process: softmax state + sigmoid->bf16 tile write ----
        #pragma unroll
        for (int u = 0; u < 16; ++u)
            if (u < nu) {
                const int q = qt * 16 + u;
                const float v = vv[u];
                s += __expf(v);
                am = (v > m2) ? q : am;     // strict >: first max
                m2 = fmaxf(m2, v);
                xt = (q == tgv) ? v : xt;
                const float g = __builtin_amdgcn_rcpf(1.f + __expf(-v));
                *(short*)(tbq + ((u * 1024 + 2 * tid) ^ ((u & 7) << 4))) =
                    f2bf(g);
            }

        __syncthreads();   // publishes tile[qt&1]; qt+1 writes hit the OTHER
                           // buffer, qt+2's reuse is fenced by qt+1's barrier

        // ---- MFMA phase: one-hot GEMM, inputs bit-identical to R2 ----
        if (w < 3) {
            f32x4 acc = {0.f, 0.f, 0.f, 0.f};
            #pragma unroll
            for (int kc = 0; kc < 16; ++kc) {
                const short8 av = *(const short8*)(tbq +
                    ((m * 1024 + kc * 64 + quad * 16) ^ ((m & 7) << 4)));
                const unsigned long long tw =
                    *(const unsigned long long*)&tgt8[kc * 32 + quad * 8];
                short8 bv;
                #pragma unroll
                for (int j = 0; j < 8; ++j)
                    bv[j] = ((int)((tw >> (8 * j)) & 255) == cv)
                                ? (short)0x3F80 : (short)0;
                acc = __builtin_amdgcn_mfma_f32_16x16x32_bf16(av, bv, acc,
                                                              0, 0, 0);
            }
            // epilogue: D row = quad*4+reg (q), col = m (+16*w)
            // qt=6 rows 4..15 read stale tile rows -> D rows >=100, skipped
            if (!(w == 2 && m > 8)) {
                #pragma unroll
                for (int reg = 0; reg < 4; ++reg) {
                    const int q = qt * 16 + quad * 4 + reg;
                    if (q < 100)
                        atomicAdd(&inter_ext[(size_t)(b * Q + q) * Cp1 +
                                             w * 16 + m], acc[reg]);
                }
            }
        }
    }

    // ---- softmax epilogue (identical math to verified R2) ----
    float ce = 0.f;
    unsigned nv = 0u;
    if (tgv != 255) {
        ce = __logf(s) - xt;
        nv = 1u;
        atomicAdd(&counts[((size_t)b * Q + am) * C + tgv], 1u);
        atomicAdd(&ts_local[tgv], 1u);
    }
    for (int off = 32; off; off >>= 1) {
        ce += __shfl_xor(ce, off);
        nv += __shfl_xor(nv, off);
    }
    if (l == 0) { cred[w] = ce; vred[w] = nv; }
    __syncthreads();
    if (tid == 0) {
        float t = 0.f;
        unsigned n = 0u;
        #pragma unroll
        for (int i = 0; i < 8; ++i) { t += cred[i]; n += vred[i]; }
        atomicAdd(ce_sum, t);
        atomicAdd(n_valid, n);
    }
    if (tid < C) {
        unsigned t = ts_local[tid];
        if (t) atomicAdd(&tsum[b * C + tid], t);
    }
}

// Kernel C: finalize. src_sum derived from inter_ext's 41 columns. (Verified R11.)
__global__ __launch_bounds__(512) void kC(const float* __restrict__ logits,
                                          const unsigned* __restrict__ counts,
                                          const unsigned* __restrict__ tsum,
                                          const float* __restrict__ inter_ext,
                                          const float* __restrict__ ce_sum,
                                          const unsigned* __restrict__ n_valid,
                                          float* __restrict__ out) {
    int tid = threadIdx.x;
    __shared__ float dice_sum[C];
    __shared__ float ssum[B * Q];
    __shared__ float wred[8];
    __shared__ float s_lce;
    if (tid < C) dice_sum[tid] = 0.f;
    if (tid < B * Q) {                     // src_sum[bq] = sum of all 41 cols
        const float* r = inter_ext + (size_t)tid * Cp1;
        float t = 0.f;
        #pragma unroll
        for (int c = 0; c < Cp1; ++c) t += r[c];
        ssum[tid] = t;
    }

    float ce_acc = 0.f;
    for (int i = tid; i < B * Q; i += 512) {
        const unsigned* cnt = counts + (size_t)i * C;
        unsigned best = 0;
        int tc = C;
        #pragma unroll
        for (int c = 0; c < C; ++c) {
            unsigned v = cnt[c];
            if (v > best) { best = v; tc = c; }
        }
        if (tc != C) {
            const float* lg = logits + (size_t)i * Cp1;
            float mm = -INFINITY, xt = 0.f;
            #pragma unroll
            for (int c = 0; c < Cp1; ++c) {
                float v = lg[c];
                mm = fmaxf(mm, v);
                if (c == tc) xt = v;
            }
            float ss = 0.f;
            #pragma unroll
            for (int c = 0; c < Cp1; ++c) ss += __expf(lg[c] - mm);
            float nll = mm + __logf(ss) - xt;
            float p = __expf(-nll);
            float om = 1.f - p;
            ce_acc += om * om * nll;
        }
    }
    for (int off = 32; off; off >>= 1) ce_acc += __shfl_xor(ce_acc, off);
    if ((tid & 63) == 0) wred[tid >> 6] = ce_acc;
    __syncthreads();                        // also publishes ssum + dice_sum init
    if (tid == 0) {
        float t = 0.f;
        for (int w = 0; w < 8; ++w) t += wred[w];
        s_lce = t;
    }

    for (int i = tid; i < B * Q * C; i += 512) {
        int bq = i / C, c = i - bq * C;
        float denom = ssum[bq] + (float)tsum[(bq / Q) * C + c] + 1e-8f;
        atomicAdd(&dice_sum[c], 2.f * inter_ext[(size_t)bq * Cp1 + c] / denom);
    }
    __syncthreads();

    if (tid == 0) {
        float dl = 0.f;
        for (int c = 0; c < C; ++c) {
            unsigned ts = tsum[c] + tsum[C + c] + tsum[2 * C + c] + tsum[3 * C + c];
            if (ts > 0) dl += 1.f - dice_sum[c] * (1.f / (B * Q));
        }
        dl *= (1.f / C);
        float ce_mask = ce_sum[0] / fmaxf((float)n_valid[0], 1.f);
        float lce = s_lce * (1.f / (B * Q));
        out[0] = 2.f * lce + 5.f * ce_mask + 5.f * dl;
    }
}

extern "C" void kernel_launch(void* const* d_in, const int* in_sizes, int n_in,
                              void* d_out, int out_size, void* d_ws, size_t ws_size,
                              hipStream_t stream) {
    const float* logits  = (const float*)d_in[0];   // [B,Q,41] f32
    const float* masks   = (const float*)d_in[1];   // [B,Q,H,W] f32
    const int*   targets = (const int*)d_in[2];     // [B,H,W] int32
    float* out = (float*)d_out;                     // f32 scalar

    unsigned* ws        = (unsigned*)d_ws;
    unsigned* counts    = ws;                       // 16000 u32
    unsigned* tsum      = ws + 16000;               // 160 u32
    float*    ce_sum    = (float*)(ws + 16160);     // 1 f32
    unsigned* n_valid   = ws + 16161;               // 1 u32
    float*    inter_ext = (float*)(ws + 16162);     // 16400 f32

    kZ<<<64, 256, 0, stream>>>(ws, WS_WORDS);
    kF<<<FBLKS, 512, 0, stream>>>(masks, targets, counts, tsum, ce_sum, n_valid,
                                  inter_ext);
    kC<<<1, 512, 0, stream>>>(logits, counts, tsum, inter_ext, ce_sum, n_valid, out);
}

// Round 8
// 206.049 us; speedup vs baseline: 1.7445x; 1.0330x over previous
//
#include <hip/hip_runtime.h>

// Problem constants (fixed by setup_inputs)
constexpr int B = 4, Q = 100, C = 40, Cp1 = 41, HW = 65536;

// R6: verified R2 structure (512 blocks x 256 thr, 2 px/thread, float2 JIT
// loads, 48-VGPR codegen) + two targeted changes:
//  (1) inter_ext accumulation moved OUT of the qt loop: per-qt MFMA results
//      go to LDS via fire-and-forget ds_add_f32 (no vmcnt pollution; R2-R5
//      kept 2.35M global atomics in-loop, serializing every qt's s_waitcnt),
//      flushed once per block with coalesced contiguous atomics.
//  (2) R5's double-buffered tile -> 1 barrier per qt (7+1 vs R2's 14).
constexpr int FBLKS = 512;

// Workspace layout (4-byte words):
//  [0, 16000)        counts    u32 [B][Q][C]
//  [16000, 16160)    tsum      u32 [B][C]
//  [16160]           ce_sum    f32
//  [16161]           n_valid   u32
//  [16162, 32562)    inter_ext f32 [B*Q][41]   (col 40 = ignored-pixel sig sum)
constexpr int WS_WORDS = 32562;

typedef __attribute__((ext_vector_type(8))) short short8;   // 8 bf16
typedef __attribute__((ext_vector_type(4))) float f32x4;

__device__ __forceinline__ short f2bf(float f) {            // RNE f32->bf16
    unsigned u = __float_as_uint(f);
    u += 0x7FFF + ((u >> 16) & 1);
    return (short)(u >> 16);
}

__global__ void kZ(unsigned* __restrict__ ws, int n) {
    int i = blockIdx.x * blockDim.x + threadIdx.x;
    for (; i < n; i += gridDim.x * blockDim.x) ws[i] = 0u;
}

__global__ __launch_bounds__(256) void kF(const float* __restrict__ masks,
                                          const int* __restrict__ targets,
                                          unsigned* __restrict__ counts,
                                          unsigned* __restrict__ tsum,
                                          float* __restrict__ ce_sum,
                                          unsigned* __restrict__ n_valid,
                                          float* __restrict__ inter_ext) {
    // tile row = q (16 rows x 1024 B); swizzle byte-in-row ^= ((row&7)<<4)
    // (verified R2 formula) so A-frag ds_read_b128 is conflict-light.
    __shared__ __align__(16) short tileS[2][16 * 512];       // 2 x 16 KiB
    __shared__ float inter_lds[Q * Cp1];                     // 16.4 KiB
    __shared__ __align__(8) unsigned char tgt8[512];
    __shared__ unsigned ts_local[C];
    __shared__ float cred[4];
    __shared__ unsigned vred[4];

    const int tid = threadIdx.x;            // 0..255
    const int l = tid & 63, w = tid >> 6;   // wave 0..3
    const int m = l & 15, quad = l >> 4;

    const int blk = blockIdx.x;
    const int b = blk >> 7;                 // 0..3
    const int seg = blk & 127;              // 0..127
    const int p0 = seg * 512 + 2 * tid;     // px within image (2 px/thread)

    // ---- prologue (all LDS first consumed after the qt=0 barrier) ----
    const int2 tg = *(const int2*)(targets + (size_t)b * HW + p0);
    const int tg0 = tg.x, tg1 = tg.y;
    *(unsigned short*)&tgt8[2 * tid] =
        (unsigned short)((tg0 & 255) | ((tg1 & 255) << 8));
    if (tid < C) ts_local[tid] = 0u;
    #pragma unroll
    for (int i = 0; i < 17; ++i) {          // 17*256 >= 4100
        int idx = tid + i * 256;
        if (idx < Q * Cp1) inter_lds[idx] = 0.f;
    }

    const float* mp = masks + (size_t)b * Q * HW + p0;

    // per-pixel softmax state (2 px/thread) — formulas/order == verified R2
    float m20 = -INFINITY, m21 = -INFINITY;
    float s0 = 0.f, s1 = 0.f, xt0 = 0.f, xt1 = 0.f;
    int am0 = 0, am1 = 0;

    // wave MFMA role: w0 cols 0-15, w1 16-31, w2 32-40 (m>8 dead), w3 none
    const int cv = (w == 2 && m == 8) ? 255 : (w * 16 + m);

    for (int qt = 0; qt < 7; ++qt) {
        char* tbq = (char*)(&tileS[qt & 1][0]);
        const int nu = (qt == 6) ? 4 : 16;

        // ---- JIT float2 loads (R2-proven non-spilling shape) ----
        float2 vv[16];
        #pragma unroll
        for (int u = 0; u < 16; ++u)
            if (u < nu) vv[u] = *(const float2*)(mp + (size_t)(qt * 16 + u) * HW);

        // ---- process: softmax state + sigmoid->bf16 tile write ----
        #pragma unroll
        for (int u = 0; u < 16; ++u)
            if (u < nu) {
                const int q = qt * 16 + u;
                const float v0 = vv[u].x, v1 = vv[u].y;
                s0 += __expf(v0);
                s1 += __expf(v1);
                am0 = (v0 > m20) ? q : am0;  m20 = fmaxf(m20, v0);
                am1 = (v1 > m21) ? q : am1;  m21 = fmaxf(m21, v1);
                xt0 = (q == tg0) ? v0 : xt0;
                xt1 = (q == tg1) ? v1 : xt1;
                const float g0 = __builtin_amdgcn_rcpf(1.f + __expf(-v0));
                const float g1 = __builtin_amdgcn_rcpf(1.f + __expf(-v1));
                const unsigned pk = (unsigned)(unsigned short)f2bf(g0) |
                                    ((unsigned)(unsigned short)f2bf(g1) << 16);
                *(unsigned*)(tbq + ((u * 1024 + 4 * tid) ^ ((u & 7) << 4))) = pk;
            }

        __syncthreads();   // publishes tile[qt&1]; qt+1 writes hit the OTHER
                           // buffer (R5-verified double-buffer scheme)

        // ---- MFMA phase: one-hot GEMM, inputs bit-identical to R2/R5 ----
        if (w < 3) {
            f32x4 acc = {0.f, 0.f, 0.f, 0.f};
            #pragma unroll
            for (int kc = 0; kc < 16; ++kc) {
                const short8 av = *(const short8*)(tbq +
                    ((m * 1024 + kc * 64 + quad * 16) ^ ((m & 7) << 4)));
                const unsigned long long tw =
                    *(const unsigned long long*)&tgt8[kc * 32 + quad * 8];
                short8 bv;
                #pragma unroll
                for (int j = 0; j < 8; ++j)
                    bv[j] = ((int)((tw >> (8 * j)) & 255) == cv)
                                ? (short)0x3F80 : (short)0;
                acc = __builtin_amdgcn_mfma_f32_16x16x32_bf16(av, bv, acc,
                                                              0, 0, 0);
            }
            // epilogue into LDS: ds_add_f32 fire-and-forget (no vmcnt).
            // D row = quad*4+reg (q-within-tile), col = m (+16*w).
            // qt=6 rows 4..15 are stale -> q>=100, skipped.
            if (!(w == 2 && m > 8)) {
                #pragma unroll
                for (int reg = 0; reg < 4; ++reg) {
                    const int q = qt * 16 + quad * 4 + reg;
                    if (q < 100)
                        atomicAdd(&inter_lds[q * Cp1 + w * 16 + m], acc[reg]);
                }
            }
        }
    }

    // ---- softmax epilogue (identical math to verified R2) ----
    float ce = 0.f;
    unsigned nv = 0u;
    if (tg0 != 255) {
        ce += __logf(s0) - xt0; nv++;
        atomicAdd(&counts[((size_t)b * Q + am0) * C + tg0], 1u);
        atomicAdd(&ts_local[tg0], 1u);
    }
    if (tg1 != 255) {
        ce += __logf(s1) - xt1; nv++;
        atomicAdd(&counts[((size_t)b * Q + am1) * C + tg1], 1u);
        atomicAdd(&ts_local[tg1], 1u);
    }
    for (int off = 32; off; off >>= 1) {
        ce += __shfl_xor(ce, off);
        nv += __shfl_xor(nv, off);
    }
    if (l == 0) { cred[w] = ce; vred[w] = nv; }
    __syncthreads();    // fences last qt's inter_lds ds_adds + ts_local + cred
    if (tid == 0) {
        atomicAdd(ce_sum, cred[0] + cred[1] + cred[2] + cred[3]);
        atomicAdd(n_valid, vred[0] + vred[1] + vred[2] + vred[3]);
    }
    if (tid < C) {
        unsigned t = ts_local[tid];
        if (t) atomicAdd(&tsum[b * C + tid], t);
    }

    // ---- single coalesced inter flush (same addend set per word as R5:
    //      one contribution per block; only arrival order differs) ----
    const size_t ibase = (size_t)b * Q * Cp1;
    #pragma unroll
    for (int i = 0; i < 17; ++i) {
        int idx = tid + i * 256;
        if (idx < Q * Cp1) {
            float v = inter_lds[idx];
            if (v != 0.f) atomicAdd(&inter_ext[ibase + idx], v);
        }
    }
}

// Kernel C: finalize (verified logic; R6: 1024 threads for more TLP on the CU).
__global__ __launch_bounds__(1024) void kC(const float* __restrict__ logits,
                                           const unsigned* __restrict__ counts,
                                           const unsigned* __restrict__ tsum,
                                           const float* __restrict__ inter_ext,
                                           const float* __restrict__ ce_sum,
                                           const unsigned* __restrict__ n_valid,
                                           float* __restrict__ out) {
    int tid = threadIdx.x;
    __shared__ float dice_sum[C];
    __shared__ float ssum[B * Q];
    __shared__ float wred[16];
    __shared__ float s_lce;
    if (tid < C) dice_sum[tid] = 0.f;
    if (tid < B * Q) {                     // src_sum[bq] = sum of all 41 cols
        const float* r = inter_ext + (size_t)tid * Cp1;
        float t = 0.f;
        #pragma unroll
        for (int c = 0; c < Cp1; ++c) t += r[c];
        ssum[tid] = t;
    }

    float ce_acc = 0.f;
    for (int i = tid; i < B * Q; i += 1024) {
        const unsigned* cnt = counts + (size_t)i * C;
        unsigned best = 0;
        int tc = C;
        #pragma unroll
        for (int c = 0; c < C; ++c) {
            unsigned v = cnt[c];
            if (v > best) { best = v; tc = c; }
        }
        if (tc != C) {
            const float* lg = logits + (size_t)i * Cp1;
            float mm = -INFINITY, xt = 0.f;
            #pragma unroll
            for (int c = 0; c < Cp1; ++c) {
                float v = lg[c];
                mm = fmaxf(mm, v);
                if (c == tc) xt = v;
            }
            float ss = 0.f;
            #pragma unroll
            for (int c = 0; c < Cp1; ++c) ss += __expf(lg[c] - mm);
            float nll = mm + __logf(ss) - xt;
            float p = __expf(-nll);
            float om = 1.f - p;
            ce_acc += om * om * nll;
        }
    }
    for (int off = 32; off; off >>= 1) ce_acc += __shfl_xor(ce_acc, off);
    if ((tid & 63) == 0) wred[tid >> 6] = ce_acc;
    __syncthreads();                        // also publishes ssum + dice_sum init
    if (tid == 0) {
        float t = 0.f;
        for (int w = 0; w < 16; ++w) t += wred[w];
        s_lce = t;
    }

    for (int i = tid; i < B * Q * C; i += 1024) {
        int bq = i / C, c = i - bq * C;
        float denom = ssum[bq] + (float)tsum[(bq / Q) * C + c] + 1e-8f;
        atomicAdd(&dice_sum[c], 2.f * inter_ext[(size_t)bq * Cp1 + c] / denom);
    }
    __syncthreads();

    if (tid == 0) {
        float dl = 0.f;
        for (int c = 0; c < C; ++c) {
            unsigned ts = tsum[c] + tsum[C + c] + tsum[2 * C + c] + tsum[3 * C + c];
            if (ts > 0) dl += 1.f - dice_sum[c] * (1.f / (B * Q));
        }
        dl *= (1.f / C);
        float ce_mask = ce_sum[0] / fmaxf((float)n_valid[0], 1.f);
        float lce = s_lce * (1.f / (B * Q));
        out[0] = 2.f * lce + 5.f * ce_mask + 5.f * dl;
    }
}

extern "C" void kernel_launch(void* const* d_in, const int* in_sizes, int n_in,
                              void* d_out, int out_size, void* d_ws, size_t ws_size,
                              hipStream_t stream) {
    const float* logits  = (const float*)d_in[0];   // [B,Q,41] f32
    const float* masks   = (const float*)d_in[1];   // [B,Q,H,W] f32
    const int*   targets = (const int*)d_in[2];     // [B,H,W] int32
    float* out = (float*)d_out;                     // f32 scalar

    unsigned* ws        = (unsigned*)d_ws;
    unsigned* counts    = ws;                       // 16000 u32
    unsigned* tsum      = ws + 16000;               // 160 u32
    float*    ce_sum    = (float*)(ws + 16160);     // 1 f32
    unsigned* n_valid   = ws + 16161;               // 1 u32
    float*    inter_ext = (float*)(ws + 16162);     // 16400 f32

    kZ<<<64, 256, 0, stream>>>(ws, WS_WORDS);
    kF<<<FBLKS, 256, 0, stream>>>(masks, targets, counts, tsum, ce_sum, n_valid,
                                  inter_ext);
    kC<<<1, 1024, 0, stream>>>(logits, counts, tsum, inter_ext, ce_sum, n_valid, out);
}